// Round 8
// baseline (182.732 us; speedup 1.0000x reference)
//
#include <hip/hip_runtime.h>
#include <stdint.h>

// Shapes: B=8, Nt=Ns=1024, D=128, H=4. All I/O float32.

typedef float f32x16 __attribute__((ext_vector_type(16)));
typedef float f32x4 __attribute__((ext_vector_type(4)));
typedef short s16x8 __attribute__((ext_vector_type(8)));
typedef __bf16 bf16x8 __attribute__((ext_vector_type(8)));

__device__ __forceinline__ f32x16 mfma_bf16(s16x8 a, s16x8 b, f32x16 c) {
  return __builtin_amdgcn_mfma_f32_32x32x16_bf16(
      __builtin_bit_cast(bf16x8, a), __builtin_bit_cast(bf16x8, b), c, 0, 0, 0);
}
__device__ __forceinline__ f32x4 mfma16(s16x8 a, s16x8 b, f32x4 c) {
  return __builtin_amdgcn_mfma_f32_16x16x32_bf16(
      __builtin_bit_cast(bf16x8, a), __builtin_bit_cast(bf16x8, b), c, 0, 0, 0);
}

__device__ __forceinline__ unsigned short f2bf(float f) {
  union { float f; unsigned int i; } v; v.f = f;
  return (unsigned short)((v.i + 0x8000u) >> 16);
}
__device__ __forceinline__ float bf2f(unsigned short u) {
  union { unsigned int i; float f; } v; v.i = ((unsigned int)u) << 16; return v.f;
}
__device__ __forceinline__ s16x8 pack8(float4 a, float4 b) {
  s16x8 r;
  r[0] = (short)f2bf(a.x); r[1] = (short)f2bf(a.y);
  r[2] = (short)f2bf(a.z); r[3] = (short)f2bf(a.w);
  r[4] = (short)f2bf(b.x); r[5] = (short)f2bf(b.y);
  r[6] = (short)f2bf(b.z); r[7] = (short)f2bf(b.w);
  return r;
}
__device__ __forceinline__ f32x16 zero16() {
  f32x16 z;
#pragma unroll
  for (int i = 0; i < 16; ++i) z[i] = 0.f;
  return z;
}
__device__ __forceinline__ f32x4 zero4() {
  f32x4 z; z[0] = z[1] = z[2] = z[3] = 0.f; return z;
}

// ---- K_pre: wpP pack | W_src pack | adj bitmask | a_tgt (self-contained csum) ----
__global__ __launch_bounds__(256) void k_pre(
    const float* __restrict__ W_tgt, const float* __restrict__ W_src,
    const float* __restrict__ att_tgt,
    const float* __restrict__ W_gv, const float* __restrict__ W_out,
    const float* __restrict__ adj, const float* __restrict__ x_target,
    unsigned short* __restrict__ wpP, unsigned short* __restrict__ W_srcP,
    unsigned long long* __restrict__ abits, float* __restrict__ a_tgtT) {
  int blk = blockIdx.x, tid = threadIdx.x;
  int w = tid >> 6, lane = tid & 63;
  if (blk < 192) {
    // FFN weights -> tiled bf16: wpP[mat][kg][n][8], mat: 0=val,1=gate,2=out
    int i = blk * 256 + tid;  // 0..49151
    int r = i >> 7, c = i & 127;
    float v = (r < 256) ? W_gv[i] : W_out[i - 32768];
    int mat = (r < 128) ? 0 : ((r < 256) ? 1 : 2);
    int n = r & 127, kg = c >> 3, j = c & 7;
    wpP[mat * 16384 + (kg * 128 + n) * 8 + j] = f2bf(v);
  } else if (blk < 448) {
    // W_src -> tiled bf16 W_srcP[kg][n][8]
    int i = (blk - 192) * 256 + tid;  // 0..65535
    int n = i >> 7, c = i & 127;
    int kg = c >> 3, j = c & 7;
    W_srcP[(kg * 512 + n) * 8 + j] = f2bf(W_src[i]);
  } else if (blk < 2496) {
    // adj -> bitmask, 4 rows per block
    int row = (blk - 448) * 4 + w;  // 0..8191
    const float* ar = adj + (size_t)row * 1024;
#pragma unroll 4
    for (int it = 0; it < 16; ++it) {
      float A = ar[it * 64 + lane];
      unsigned long long bal = __ballot(A != 0.f);
      if (lane == 0) abits[row * 16 + it] = bal;
    }
  } else {
    // a_tgt: 32 rows/block; csum computed in-block (W_tgt is L2-resident)
    __shared__ float csum[512];
#pragma unroll
    for (int rep = 0; rep < 2; ++rep) {
      int idx = rep * 256 + tid;
      int h = idx >> 7, k = idx & 127;
      float acc = 0.f;
#pragma unroll 4
      for (int d = 0; d < 128; ++d)
        acc += att_tgt[h * 128 + d] * W_tgt[(h * 128 + d) * 128 + k];
      csum[idx] = acc;
    }
    __syncthreads();
    int rbase = (blk - 2496) * 32 + w * 8;
#pragma unroll
    for (int i = 0; i < 8; ++i) {
      int r = rbase + i;
      float2 xv = *(const float2*)(x_target + (size_t)r * 128 + lane * 2);
#pragma unroll
      for (int h = 0; h < 4; ++h) {
        float2 c2 = *(const float2*)&csum[h * 128 + lane * 2];
        float p = xv.x * c2.x + xv.y * c2.y;
#pragma unroll
        for (int off = 32; off; off >>= 1) p += __shfl_xor(p, off);
        if (lane == 0) a_tgtT[(((r >> 10) * 4 + h) << 10) | (r & 1023)] = p;
      }
    }
  }
}

// ---- K_hsrc: h_srcP[b*4+h][s/8][d][8] bf16 + a_src -> ES/ES2 epilogue ----
__global__ __launch_bounds__(256) void k_hsrc(
    const float* __restrict__ x_source,
    const unsigned short* __restrict__ W_srcP,
    const float* __restrict__ att_src,
    unsigned short* __restrict__ h_srcP, float* __restrict__ esrc) {
  __shared__ unsigned short As[128][136];
  __shared__ float apart[128];
  int mt = blockIdx.x >> 2, nt = blockIdx.x & 3;  // nt = head
  int nbase = nt * 128;
  int b = mt >> 3, sbase = (mt & 7) * 128;
  int tid = threadIdx.x;
  int w = tid >> 6, lane = tid & 63;
#pragma unroll
  for (int c = tid; c < 2048; c += 256) {
    int r = c >> 4, c8 = (c & 15) * 8;
    const float* src = x_source + ((size_t)(mt * 128 + r)) * 128 + c8;
    *(s16x8*)&As[r][c8] = pack8(*(const float4*)src, *(const float4*)(src + 4));
  }
  __syncthreads();
  int tl = lane & 31, q = lane >> 5;
  int wm = w >> 1, wn = w & 1;
  f32x16 acc00 = zero16(), acc01 = zero16(), acc10 = zero16(), acc11 = zero16();
#pragma unroll
  for (int kk = 0; kk < 8; ++kk) {
    int k = kk * 16 + q * 8;
    int kg = kk * 2 + q;
    s16x8 a0 = *(const s16x8*)&As[wm * 64 + tl][k];
    s16x8 a1 = *(const s16x8*)&As[wm * 64 + 32 + tl][k];
    s16x8 b0 = *(const s16x8*)(W_srcP + (size_t)(kg * 512 + nbase + wn * 64 + tl) * 8);
    s16x8 b1 = *(const s16x8*)(W_srcP + (size_t)(kg * 512 + nbase + wn * 64 + 32 + tl) * 8);
    acc00 = mfma_bf16(a0, b0, acc00);
    acc01 = mfma_bf16(a0, b1, acc01);
    acc10 = mfma_bf16(a1, b0, acc10);
    acc11 = mfma_bf16(a1, b1, acc11);
  }
  // ---- a_src epilogue: a[s] = sum_d h[s][d]*att[head][d] from fp32 accs ----
  {
    float attd0 = att_src[nt * 128 + wn * 64 + tl];
    float attd1 = att_src[nt * 128 + wn * 64 + 32 + tl];
#pragma unroll
    for (int phase = 0; phase < 2; ++phase) {
      __syncthreads();
      if (wn == phase) {
#pragma unroll
        for (int r = 0; r < 16; ++r) {
          int rp = (r & 3) + 8 * (r >> 2) + 4 * q;
          float v0 = acc00[r] * attd0 + acc01[r] * attd1;
          float v1 = acc10[r] * attd0 + acc11[r] * attd1;
#pragma unroll
          for (int off = 1; off < 32; off <<= 1) {
            v0 += __shfl_xor(v0, off);
            v1 += __shfl_xor(v1, off);
          }
          if (tl == 0) {
            if (phase == 0) {
              apart[wm * 64 + rp] = v0;
              apart[wm * 64 + 32 + rp] = v1;
            } else {
              apart[wm * 64 + rp] += v0;
              apart[wm * 64 + 32 + rp] += v1;
            }
          }
        }
      }
    }
    __syncthreads();
    if (tid < 128) {
      float a = apart[tid];
      float2 e = make_float2(__expf(a), __expf(0.2f * a));
      *(float2*)&esrc[((((size_t)(b * 4 + nt)) << 10) | (sbase + tid)) * 2] = e;
    }
  }
  __syncthreads();
#pragma unroll
  for (int r = 0; r < 16; ++r) {
    int rp = (r & 3) + 8 * (r >> 2) + 4 * q;
    As[wn * 64 + tl][wm * 64 + rp] = f2bf(acc00[r]);
    As[wn * 64 + 32 + tl][wm * 64 + rp] = f2bf(acc01[r]);
    As[wn * 64 + tl][wm * 64 + 32 + rp] = f2bf(acc10[r]);
    As[wn * 64 + 32 + tl][wm * 64 + 32 + rp] = f2bf(acc11[r]);
  }
  __syncthreads();
  size_t base = ((size_t)(b * 4 + nt)) << 17;
#pragma unroll
  for (int c = tid; c < 2048; c += 256) {
    int d = c & 127, sgl = c >> 7;
    *(uint4*)(h_srcP + base + (size_t)((sbase >> 3) + sgl) * 1024 + d * 8) =
        *(const uint4*)&As[d][sgl * 8];
  }
}

// ---- K_attn: all 4 heads per block + head-mean + bias + residual + LN1 -> x1 bf16 ----
// grid 256 = b(&7) x tt(>>3); 1024 threads = 16 waves: head = w&3, sq = w>>2.
__global__ __launch_bounds__(1024) void k_attn(
    const unsigned short* __restrict__ h_srcP,
    const float* __restrict__ a_tgtT, const float* __restrict__ esrc,
    const unsigned int* __restrict__ abits32,
    const float* __restrict__ x_target, const float* __restrict__ gat_bias,
    const float* __restrict__ ln1_g, const float* __restrict__ ln1_b,
    unsigned short* __restrict__ x1) {
  extern __shared__ float dsm[];  // 64 KB: [0,8192f)=es[4][1024][2]; later red[4][32][128]
  __shared__ unsigned int bmask[32][33];
  __shared__ float eab[4][32], ea2b[4][32], scb[4][32];
  __shared__ float zpart[4][4][32];
  int b = blockIdx.x & 7, tt = blockIdx.x >> 3;
  int tbase = tt * 32;
  int tid = threadIdx.x, w = tid >> 6, lane = tid & 63;
  {
    const float* ep = esrc + ((size_t)b << 13);
    *(float4*)&dsm[tid * 8] = *(const float4*)(ep + tid * 8);
    *(float4*)&dsm[tid * 8 + 4] = *(const float4*)(ep + tid * 8 + 4);
  }
  {
    int r = tid >> 5, c = tid & 31;
    bmask[r][c] = abits32[((size_t)(b * 1024 + tbase + r)) * 32 + c];
  }
  if (tid < 128) {
    int h = tid >> 5, r = tid & 31;
    float at = a_tgtT[((b * 4 + h) << 10) + tbase + r];
    eab[h][r] = __expf(at);
    ea2b[h][r] = __expf(0.2f * at);
  }
  __syncthreads();
  int head = w & 3, sq = w >> 2, tl = lane & 31, q = lane >> 5;
  float EA = eab[head][tl], EA2 = ea2b[head][tl];
  f32x16 acc[4];
#pragma unroll
  for (int i = 0; i < 4; ++i) acc[i] = zero16();
  float z = 0.f;
  const float* asl = dsm + (head << 11);
  const unsigned short* bbase = h_srcP + (((size_t)(b * 4 + head)) << 17);
#pragma unroll 2
  for (int kk = 0; kk < 16; ++kk) {
    int sA = sq * 256 + kk * 16 + q * 8;
    const unsigned short* hp = bbase + (size_t)((sA >> 3) * 128 + tl) * 8;
    s16x8 b0 = *(const s16x8*)hp;
    s16x8 b1 = *(const s16x8*)(hp + 256);
    s16x8 b2 = *(const s16x8*)(hp + 512);
    s16x8 b3 = *(const s16x8*)(hp + 768);
    unsigned int wbits = bmask[tl][sA >> 5] >> (sA & 31);
    const float4* ev = (const float4*)&asl[sA * 2];
    float4 e0 = ev[0], e1 = ev[1], e2 = ev[2], e3 = ev[3];
    int4 afw;
#define PAIR(EV, J0, OUT)                                              \
  {                                                                    \
    float q1a = EA * EV.x, q0a = EA2 * EV.y;                           \
    float pa = (q1a >= 1.f) ? q1a : q0a;                               \
    unsigned pau = __float_as_uint(pa) & (0u - ((wbits >> (J0)) & 1u)); \
    float q1b = EA * EV.z, q0b = EA2 * EV.w;                           \
    float pb = (q1b >= 1.f) ? q1b : q0b;                               \
    unsigned pbu = __float_as_uint(pb) & (0u - ((wbits >> (J0 + 1)) & 1u)); \
    z += __uint_as_float(pau) + __uint_as_float(pbu);                  \
    OUT = (int)__builtin_amdgcn_perm(pbu + 0x8000u, pau + 0x8000u, 0x07060302u); \
  }
    PAIR(e0, 0, afw.x)
    PAIR(e1, 2, afw.y)
    PAIR(e2, 4, afw.z)
    PAIR(e3, 6, afw.w)
#undef PAIR
    s16x8 af = __builtin_bit_cast(s16x8, afw);
    acc[0] = mfma_bf16(af, b0, acc[0]);
    acc[1] = mfma_bf16(af, b1, acc[1]);
    acc[2] = mfma_bf16(af, b2, acc[2]);
    acc[3] = mfma_bf16(af, b3, acc[3]);
  }
  z += __shfl_xor(z, 32);
  if (q == 0) zpart[head][sq][tl] = z;
  __syncthreads();  // all waves done with es region
  if (tid < 128) {
    int h = tid >> 5, r = tid & 31;
    float Z = zpart[h][0][r] + zpart[h][1][r] + zpart[h][2][r] + zpart[h][3][r];
    scb[h][r] = (Z > 0.f) ? 0.25f / Z : 0.f;
  }
  float (*red)[32][128] = (float(*)[32][128])dsm;
#pragma unroll
  for (int sqi = 0; sqi < 4; ++sqi) {
    if (sqi) __syncthreads();
    if (sq == sqi) {
#pragma unroll
      for (int dt = 0; dt < 4; ++dt)
#pragma unroll
        for (int r = 0; r < 16; ++r) {
          int rp = (r & 3) + 8 * (r >> 2) + 4 * q;
          if (sqi == 0)
            red[head][rp][dt * 32 + tl] = acc[dt][r];
          else
            red[head][rp][dt * 32 + tl] += acc[dt][r];
        }
    }
  }
  __syncthreads();
  // final: u = x_target + bias + sum_h scb*red; LN1; store bf16 x1
  {
    int r = tid >> 5, dg = tid & 31, d0 = dg * 4;
    size_t grow = (size_t)(b * 1024 + tbase + r);
    float4 xa = *(const float4*)(x_target + grow * 128 + d0);
    float4 ga = *(const float4*)(gat_bias + d0);
    float s0 = scb[0][r], s1 = scb[1][r], s2 = scb[2][r], s3 = scb[3][r];
    float4 r0 = *(const float4*)&red[0][r][d0];
    float4 r1 = *(const float4*)&red[1][r][d0];
    float4 r2 = *(const float4*)&red[2][r][d0];
    float4 r3 = *(const float4*)&red[3][r][d0];
    float u[4];
    u[0] = xa.x + ga.x + s0 * r0.x + s1 * r1.x + s2 * r2.x + s3 * r3.x;
    u[1] = xa.y + ga.y + s0 * r0.y + s1 * r1.y + s2 * r2.y + s3 * r3.y;
    u[2] = xa.z + ga.z + s0 * r0.z + s1 * r1.z + s2 * r2.z + s3 * r3.z;
    u[3] = xa.w + ga.w + s0 * r0.w + s1 * r1.w + s2 * r2.w + s3 * r3.w;
    float s = u[0] + u[1] + u[2] + u[3];
    float ss = u[0] * u[0] + u[1] * u[1] + u[2] * u[2] + u[3] * u[3];
#pragma unroll
    for (int off = 1; off < 32; off <<= 1) {
      s += __shfl_xor(s, off);
      ss += __shfl_xor(ss, off);
    }
    float mu = s * (1.f / 128.f);
    float var = ss * (1.f / 128.f) - mu * mu;
    float rstd = rsqrtf(var + 1e-5f);
    float4 g4 = *(const float4*)(ln1_g + d0);
    float4 b4 = *(const float4*)(ln1_b + d0);
    unsigned short o0 = f2bf((u[0] - mu) * rstd * g4.x + b4.x);
    unsigned short o1 = f2bf((u[1] - mu) * rstd * g4.y + b4.y);
    unsigned short o2 = f2bf((u[2] - mu) * rstd * g4.z + b4.z);
    unsigned short o3 = f2bf((u[3] - mu) * rstd * g4.w + b4.w);
    uint2 ov;
    ov.x = (unsigned)o0 | ((unsigned)o1 << 16);
    ov.y = (unsigned)o2 | ((unsigned)o3 << 16);
    *(uint2*)(x1 + grow * 128 + d0) = ov;
  }
}

// ---- K_ffn: x1 -> SwiGLU FFN + residual + LN2 (16 rows/block) ----
__global__ __launch_bounds__(256) void k_ffn(
    const unsigned short* __restrict__ x1,
    const unsigned short* __restrict__ wpP,
    const float* __restrict__ ln2_g, const float* __restrict__ ln2_b,
    float* __restrict__ out) {
  __shared__ unsigned short x1s[16][136];
  __shared__ unsigned short hids[16][136];
  __shared__ float yred[16][128];
  int tid = threadIdx.x;
  int row = tid >> 4, cg = tid & 15;
  size_t rbase = (size_t)blockIdx.x * 16;
  *(s16x8*)&x1s[row][cg * 8] =
      *(const s16x8*)(x1 + (rbase + row) * 128 + cg * 8);
  __syncthreads();
  int w = tid >> 6, lane = tid & 63, n16 = lane & 15, q2 = lane >> 4;
  int nb = w * 32;
  f32x4 accv0 = zero4(), accv1 = zero4(), accg0 = zero4(), accg1 = zero4();
#pragma unroll
  for (int kk = 0; kk < 4; ++kk) {
    s16x8 a = *(const s16x8*)&x1s[n16][kk * 32 + q2 * 8];
    int kg = kk * 4 + q2;
    const unsigned short* bp = wpP + (size_t)(kg * 128 + nb + n16) * 8;
    accv0 = mfma16(a, *(const s16x8*)bp, accv0);
    accv1 = mfma16(a, *(const s16x8*)(bp + 128), accv1);
    accg0 = mfma16(a, *(const s16x8*)(bp + 16384), accg0);
    accg1 = mfma16(a, *(const s16x8*)(bp + 16384 + 128), accg1);
  }
#pragma unroll
  for (int r = 0; r < 4; ++r) {
    int m = q2 * 4 + r;
    float g0 = accg0[r], g1 = accg1[r];
    float h0 = accv0[r] * g0 / (1.f + __expf(-g0));
    float h1 = accv1[r] * g1 / (1.f + __expf(-g1));
    hids[m][nb + n16] = f2bf(h0);
    hids[m][nb + 16 + n16] = f2bf(h1);
  }
  __syncthreads();
  f32x4 acco0 = zero4(), acco1 = zero4();
#pragma unroll
  for (int kk = 0; kk < 4; ++kk) {
    s16x8 a = *(const s16x8*)&hids[n16][kk * 32 + q2 * 8];
    int kg = kk * 4 + q2;
    const unsigned short* bp = wpP + 32768 + (size_t)(kg * 128 + nb + n16) * 8;
    acco0 = mfma16(a, *(const s16x8*)bp, acco0);
    acco1 = mfma16(a, *(const s16x8*)(bp + 128), acco1);
  }
#pragma unroll
  for (int r = 0; r < 4; ++r) {
    int m = q2 * 4 + r;
    yred[m][nb + n16] = bf2f(x1s[m][nb + n16]) + acco0[r];
    yred[m][nb + 16 + n16] = bf2f(x1s[m][nb + 16 + n16]) + acco1[r];
  }
  __syncthreads();
  {
    int k0 = (tid & 15) * 8;
    float y[8];
#pragma unroll
    for (int i = 0; i < 8; ++i) y[i] = yred[row][k0 + i];
    float s = 0.f, ss = 0.f;
#pragma unroll
    for (int i = 0; i < 8; ++i) { s += y[i]; ss += y[i] * y[i]; }
#pragma unroll
    for (int off = 1; off < 16; off <<= 1) { s += __shfl_xor(s, off); ss += __shfl_xor(ss, off); }
    float mu = s * (1.f / 128.f);
    float var = ss * (1.f / 128.f) - mu * mu;
    float rstd = rsqrtf(var + 1e-5f);
    float4 o0, o1;
    o0.x = (y[0] - mu) * rstd * ln2_g[k0] + ln2_b[k0];
    o0.y = (y[1] - mu) * rstd * ln2_g[k0 + 1] + ln2_b[k0 + 1];
    o0.z = (y[2] - mu) * rstd * ln2_g[k0 + 2] + ln2_b[k0 + 2];
    o0.w = (y[3] - mu) * rstd * ln2_g[k0 + 3] + ln2_b[k0 + 3];
    o1.x = (y[4] - mu) * rstd * ln2_g[k0 + 4] + ln2_b[k0 + 4];
    o1.y = (y[5] - mu) * rstd * ln2_g[k0 + 5] + ln2_b[k0 + 5];
    o1.z = (y[6] - mu) * rstd * ln2_g[k0 + 6] + ln2_b[k0 + 6];
    o1.w = (y[7] - mu) * rstd * ln2_g[k0 + 7] + ln2_b[k0 + 7];
    *(float4*)(out + (rbase + row) * 128 + k0) = o0;
    *(float4*)(out + (rbase + row) * 128 + k0 + 4) = o1;
  }
}

// ---------------- launch ----------------
extern "C" void kernel_launch(void* const* d_in, const int* in_sizes, int n_in,
                              void* d_out, int out_size, void* d_ws, size_t ws_size,
                              hipStream_t stream) {
  const float* x_target = (const float*)d_in[0];
  const float* adj      = (const float*)d_in[1];
  const float* x_source = (const float*)d_in[2];
  const float* W_src    = (const float*)d_in[3];
  const float* W_tgt    = (const float*)d_in[4];
  const float* att_src  = (const float*)d_in[5];
  const float* att_tgt  = (const float*)d_in[6];
  const float* gat_bias = (const float*)d_in[7];
  const float* ln1_g    = (const float*)d_in[8];
  const float* ln1_b    = (const float*)d_in[9];
  const float* W_gv     = (const float*)d_in[10];
  const float* W_out    = (const float*)d_in[11];
  const float* ln2_g    = (const float*)d_in[12];
  const float* ln2_b    = (const float*)d_in[13];

  float* ws_f = (float*)d_ws;
  // workspace layout (float-element offsets)
  const size_t OFF_AT = 0;        // a_tgtT [8][4][1024] = 32768 f
  const size_t OFF_ES = 32768;    // esrc float2 [8][4][1024] = 65536 f
  const size_t OFF_AB = 98304;    // abits u64 [8192][16] = 262144 f
  const size_t OFF_X1 = 360448;   // x1 bf16 [8192][128] = 524288 f
  const size_t OFF_HS = 884736;   // h_srcP bf16 [32][131072] = 2097152 f
  unsigned short* x1     = (unsigned short*)(ws_f + OFF_X1);
  unsigned short* h_srcP = (unsigned short*)(ws_f + OFF_HS);
  unsigned short* wpP    = h_srcP + (size_t)4194304;  // 49152 bf16
  unsigned short* W_srcP = wpP + 49152;               // 65536 bf16

  k_pre<<<2752, 256, 0, stream>>>(W_tgt, W_src, att_tgt, W_gv, W_out, adj,
                                  x_target, wpP, W_srcP,
                                  (unsigned long long*)(ws_f + OFF_AB),
                                  ws_f + OFF_AT);
  k_hsrc<<<256, 256, 0, stream>>>(x_source, W_srcP, att_src, h_srcP,
                                  ws_f + OFF_ES);
  k_attn<<<256, 1024, 65536, stream>>>(h_srcP, ws_f + OFF_AT, ws_f + OFF_ES,
                                       (const unsigned int*)(ws_f + OFF_AB),
                                       x_target, gat_bias, ln1_g, ln1_b, x1);
  k_ffn<<<512, 256, 0, stream>>>(x1, wpP, ln2_g, ln2_b, (float*)d_out);
}

// Round 9
// 154.582 us; speedup vs baseline: 1.1821x; 1.1821x over previous
//
#include <hip/hip_runtime.h>
#include <stdint.h>

// Shapes: B=8, Nt=Ns=1024, D=128, H=4. All I/O float32.

typedef float f32x16 __attribute__((ext_vector_type(16)));
typedef float f32x4 __attribute__((ext_vector_type(4)));
typedef short s16x8 __attribute__((ext_vector_type(8)));
typedef __bf16 bf16x8 __attribute__((ext_vector_type(8)));

__device__ __forceinline__ f32x16 mfma_bf16(s16x8 a, s16x8 b, f32x16 c) {
  return __builtin_amdgcn_mfma_f32_32x32x16_bf16(
      __builtin_bit_cast(bf16x8, a), __builtin_bit_cast(bf16x8, b), c, 0, 0, 0);
}
__device__ __forceinline__ f32x4 mfma16(s16x8 a, s16x8 b, f32x4 c) {
  return __builtin_amdgcn_mfma_f32_16x16x32_bf16(
      __builtin_bit_cast(bf16x8, a), __builtin_bit_cast(bf16x8, b), c, 0, 0, 0);
}

__device__ __forceinline__ unsigned short f2bf(float f) {
  union { float f; unsigned int i; } v; v.f = f;
  return (unsigned short)((v.i + 0x8000u) >> 16);
}
__device__ __forceinline__ float bf2f(unsigned short u) {
  union { unsigned int i; float f; } v; v.i = ((unsigned int)u) << 16; return v.f;
}
__device__ __forceinline__ s16x8 pack8(float4 a, float4 b) {
  s16x8 r;
  r[0] = (short)f2bf(a.x); r[1] = (short)f2bf(a.y);
  r[2] = (short)f2bf(a.z); r[3] = (short)f2bf(a.w);
  r[4] = (short)f2bf(b.x); r[5] = (short)f2bf(b.y);
  r[6] = (short)f2bf(b.z); r[7] = (short)f2bf(b.w);
  return r;
}
__device__ __forceinline__ f32x16 zero16() {
  f32x16 z;
#pragma unroll
  for (int i = 0; i < 16; ++i) z[i] = 0.f;
  return z;
}
__device__ __forceinline__ f32x4 zero4() {
  f32x4 z; z[0] = z[1] = z[2] = z[3] = 0.f; return z;
}

// ---- K_pre: wpP pack | W_src pack | csum_tgt | adj bitmask (ballot-free) ----
__global__ __launch_bounds__(256) void k_pre(
    const float* __restrict__ W_tgt, const float* __restrict__ W_src,
    const float* __restrict__ att_tgt,
    const float* __restrict__ W_gv, const float* __restrict__ W_out,
    const float* __restrict__ adj,
    unsigned short* __restrict__ wpP, unsigned short* __restrict__ W_srcP,
    float* __restrict__ ws_c, unsigned int* __restrict__ abits32) {
  int blk = blockIdx.x, tid = threadIdx.x;
  if (blk < 192) {
    // FFN weights -> tiled bf16: wpP[mat][kg][n][8], mat: 0=val,1=gate,2=out
    int i = blk * 256 + tid;  // 0..49151
    int r = i >> 7, c = i & 127;
    float v = (r < 256) ? W_gv[i] : W_out[i - 32768];
    int mat = (r < 128) ? 0 : ((r < 256) ? 1 : 2);
    int n = r & 127, kg = c >> 3, j = c & 7;
    wpP[mat * 16384 + (kg * 128 + n) * 8 + j] = f2bf(v);
  } else if (blk < 448) {
    // W_src -> tiled bf16 W_srcP[kg][n][8]
    int i = (blk - 192) * 256 + tid;  // 0..65535
    int n = i >> 7, c = i & 127;
    int kg = c >> 3, j = c & 7;
    W_srcP[(kg * 512 + n) * 8 + j] = f2bf(W_src[i]);
  } else if (blk < 452) {
    // csum_tgt[h][k] = sum_d att_tgt[h][d] * W_tgt[h*128+d][k]
    __shared__ float part[2][128];
    int h = blk - 448;
    int k = tid & 127, dh = tid >> 7;
    float acc = 0.f;
#pragma unroll 4
    for (int i = 0; i < 64; ++i) {
      int d = dh * 64 + i;
      acc += att_tgt[h * 128 + d] * W_tgt[(h * 128 + d) * 128 + k];
    }
    part[dh][k] = acc;
    __syncthreads();
    if (tid < 128) ws_c[h * 128 + k] = part[0][k] + part[1][k];
  } else {
    // adj -> bitmask: one thread = one 32-bit word = one 128B line. No cross-lane.
    int g = (blk - 452) * 256 + tid;  // 0..262143
    const float* ap = adj + (size_t)g * 32;
    unsigned int bits = 0;
#pragma unroll
    for (int it = 0; it < 8; ++it) {
      float4 v = *(const float4*)(ap + it * 4);
      bits |= (v.x != 0.f ? 1u : 0u) << (it * 4);
      bits |= (v.y != 0.f ? 1u : 0u) << (it * 4 + 1);
      bits |= (v.z != 0.f ? 1u : 0u) << (it * 4 + 2);
      bits |= (v.w != 0.f ? 1u : 0u) << (it * 4 + 3);
    }
    abits32[g] = bits;
  }
}

// ---- K_hsrc: h_srcP[b*4+h][s/8][d][8] bf16 + a_src -> ES/ES2 epilogue ----
__global__ __launch_bounds__(256) void k_hsrc(
    const float* __restrict__ x_source,
    const unsigned short* __restrict__ W_srcP,
    const float* __restrict__ att_src,
    unsigned short* __restrict__ h_srcP, float* __restrict__ esrc) {
  __shared__ unsigned short As[128][136];
  __shared__ float apart[128];
  int mt = blockIdx.x >> 2, nt = blockIdx.x & 3;  // nt = head
  int nbase = nt * 128;
  int b = mt >> 3, sbase = (mt & 7) * 128;
  int tid = threadIdx.x;
  int w = tid >> 6, lane = tid & 63;
#pragma unroll
  for (int c = tid; c < 2048; c += 256) {
    int r = c >> 4, c8 = (c & 15) * 8;
    const float* src = x_source + ((size_t)(mt * 128 + r)) * 128 + c8;
    *(s16x8*)&As[r][c8] = pack8(*(const float4*)src, *(const float4*)(src + 4));
  }
  __syncthreads();
  int tl = lane & 31, q = lane >> 5;
  int wm = w >> 1, wn = w & 1;
  f32x16 acc00 = zero16(), acc01 = zero16(), acc10 = zero16(), acc11 = zero16();
#pragma unroll
  for (int kk = 0; kk < 8; ++kk) {
    int k = kk * 16 + q * 8;
    int kg = kk * 2 + q;
    s16x8 a0 = *(const s16x8*)&As[wm * 64 + tl][k];
    s16x8 a1 = *(const s16x8*)&As[wm * 64 + 32 + tl][k];
    s16x8 b0 = *(const s16x8*)(W_srcP + (size_t)(kg * 512 + nbase + wn * 64 + tl) * 8);
    s16x8 b1 = *(const s16x8*)(W_srcP + (size_t)(kg * 512 + nbase + wn * 64 + 32 + tl) * 8);
    acc00 = mfma_bf16(a0, b0, acc00);
    acc01 = mfma_bf16(a0, b1, acc01);
    acc10 = mfma_bf16(a1, b0, acc10);
    acc11 = mfma_bf16(a1, b1, acc11);
  }
  // ---- a_src epilogue: a[s] = sum_d h[s][d]*att[head][d] from fp32 accs ----
  {
    float attd0 = att_src[nt * 128 + wn * 64 + tl];
    float attd1 = att_src[nt * 128 + wn * 64 + 32 + tl];
#pragma unroll
    for (int phase = 0; phase < 2; ++phase) {
      __syncthreads();
      if (wn == phase) {
#pragma unroll
        for (int r = 0; r < 16; ++r) {
          int rp = (r & 3) + 8 * (r >> 2) + 4 * q;
          float v0 = acc00[r] * attd0 + acc01[r] * attd1;
          float v1 = acc10[r] * attd0 + acc11[r] * attd1;
#pragma unroll
          for (int off = 1; off < 32; off <<= 1) {
            v0 += __shfl_xor(v0, off);
            v1 += __shfl_xor(v1, off);
          }
          if (tl == 0) {
            if (phase == 0) {
              apart[wm * 64 + rp] = v0;
              apart[wm * 64 + 32 + rp] = v1;
            } else {
              apart[wm * 64 + rp] += v0;
              apart[wm * 64 + 32 + rp] += v1;
            }
          }
        }
      }
    }
    __syncthreads();
    if (tid < 128) {
      float a = apart[tid];
      float2 e = make_float2(__expf(a), __expf(0.2f * a));
      *(float2*)&esrc[((((size_t)(b * 4 + nt)) << 10) | (sbase + tid)) * 2] = e;
    }
  }
  __syncthreads();
#pragma unroll
  for (int r = 0; r < 16; ++r) {
    int rp = (r & 3) + 8 * (r >> 2) + 4 * q;
    As[wn * 64 + tl][wm * 64 + rp] = f2bf(acc00[r]);
    As[wn * 64 + 32 + tl][wm * 64 + rp] = f2bf(acc01[r]);
    As[wn * 64 + tl][wm * 64 + 32 + rp] = f2bf(acc10[r]);
    As[wn * 64 + 32 + tl][wm * 64 + 32 + rp] = f2bf(acc11[r]);
  }
  __syncthreads();
  size_t base = ((size_t)(b * 4 + nt)) << 17;
#pragma unroll
  for (int c = tid; c < 2048; c += 256) {
    int d = c & 127, sgl = c >> 7;
    *(uint4*)(h_srcP + base + (size_t)((sbase >> 3) + sgl) * 1024 + d * 8) =
        *(const uint4*)&As[d][sgl * 8];
  }
}

// ---- K_attn: all 4 heads per block + head-mean + bias + residual + LN1 -> x1 bf16 ----
// grid 256 = b(&7) x tt(>>3); 1024 threads = 16 waves: head = w&3, sq = w>>2.
__global__ __launch_bounds__(1024) void k_attn(
    const unsigned short* __restrict__ h_srcP,
    const float* __restrict__ ws_c, const float* __restrict__ esrc,
    const unsigned int* __restrict__ abits32,
    const float* __restrict__ x_target, const float* __restrict__ gat_bias,
    const float* __restrict__ ln1_g, const float* __restrict__ ln1_b,
    unsigned short* __restrict__ x1) {
  extern __shared__ float dsm[];  // 64 KB: [0,8192f)=es[4][1024][2]; later red[4][32][128]
  __shared__ unsigned int bmask[32][33];
  __shared__ float eab[4][32], ea2b[4][32], scb[4][32];
  __shared__ float zpart[4][4][32];
  int b = blockIdx.x & 7, tt = blockIdx.x >> 3;
  int tbase = tt * 32;
  int tid = threadIdx.x, w = tid >> 6, lane = tid & 63;
  {
    const float* ep = esrc + ((size_t)b << 13);
    *(float4*)&dsm[tid * 8] = *(const float4*)(ep + tid * 8);
    *(float4*)&dsm[tid * 8 + 4] = *(const float4*)(ep + tid * 8 + 4);
  }
  {
    int r = tid >> 5, c = tid & 31;
    bmask[r][c] = abits32[((size_t)(b * 1024 + tbase + r)) * 32 + c];
  }
  // inline a_tgt: wave w computes 8 (h,r) dots; h uniform per wave
  {
    int p0 = w * 8;
    int h = p0 >> 5;
    float2 c2 = *(const float2*)(ws_c + h * 128 + lane * 2);
#pragma unroll
    for (int i = 0; i < 8; ++i) {
      int r = (p0 + i) & 31;
      float2 xv = *(const float2*)(x_target +
                                   ((size_t)(b * 1024 + tbase + r)) * 128 + lane * 2);
      float p = xv.x * c2.x + xv.y * c2.y;
#pragma unroll
      for (int off = 32; off; off >>= 1) p += __shfl_xor(p, off);
      if (lane == 0) {
        eab[h][r] = __expf(p);
        ea2b[h][r] = __expf(0.2f * p);
      }
    }
  }
  __syncthreads();
  int head = w & 3, sq = w >> 2, tl = lane & 31, q = lane >> 5;
  float EA = eab[head][tl], EA2 = ea2b[head][tl];
  f32x16 acc[4];
#pragma unroll
  for (int i = 0; i < 4; ++i) acc[i] = zero16();
  float z = 0.f;
  const float* asl = dsm + (head << 11);
  const unsigned short* bbase = h_srcP + (((size_t)(b * 4 + head)) << 17);
#pragma unroll 2
  for (int kk = 0; kk < 16; ++kk) {
    int sA = sq * 256 + kk * 16 + q * 8;
    const unsigned short* hp = bbase + (size_t)((sA >> 3) * 128 + tl) * 8;
    s16x8 b0 = *(const s16x8*)hp;
    s16x8 b1 = *(const s16x8*)(hp + 256);
    s16x8 b2 = *(const s16x8*)(hp + 512);
    s16x8 b3 = *(const s16x8*)(hp + 768);
    unsigned int wbits = bmask[tl][sA >> 5] >> (sA & 31);
    const float4* ev = (const float4*)&asl[sA * 2];
    float4 e0 = ev[0], e1 = ev[1], e2 = ev[2], e3 = ev[3];
    int4 afw;
#define PAIR(EV, J0, OUT)                                              \
  {                                                                    \
    float q1a = EA * EV.x, q0a = EA2 * EV.y;                           \
    float pa = (q1a >= 1.f) ? q1a : q0a;                               \
    unsigned pau = __float_as_uint(pa) & (0u - ((wbits >> (J0)) & 1u)); \
    float q1b = EA * EV.z, q0b = EA2 * EV.w;                           \
    float pb = (q1b >= 1.f) ? q1b : q0b;                               \
    unsigned pbu = __float_as_uint(pb) & (0u - ((wbits >> (J0 + 1)) & 1u)); \
    z += __uint_as_float(pau) + __uint_as_float(pbu);                  \
    OUT = (int)__builtin_amdgcn_perm(pbu + 0x8000u, pau + 0x8000u, 0x07060302u); \
  }
    PAIR(e0, 0, afw.x)
    PAIR(e1, 2, afw.y)
    PAIR(e2, 4, afw.z)
    PAIR(e3, 6, afw.w)
#undef PAIR
    s16x8 af = __builtin_bit_cast(s16x8, afw);
    acc[0] = mfma_bf16(af, b0, acc[0]);
    acc[1] = mfma_bf16(af, b1, acc[1]);
    acc[2] = mfma_bf16(af, b2, acc[2]);
    acc[3] = mfma_bf16(af, b3, acc[3]);
  }
  z += __shfl_xor(z, 32);
  if (q == 0) zpart[head][sq][tl] = z;
  __syncthreads();  // all waves done with es region
  if (tid < 128) {
    int h = tid >> 5, r = tid & 31;
    float Z = zpart[h][0][r] + zpart[h][1][r] + zpart[h][2][r] + zpart[h][3][r];
    scb[h][r] = (Z > 0.f) ? 0.25f / Z : 0.f;
  }
  float (*red)[32][128] = (float(*)[32][128])dsm;
#pragma unroll
  for (int sqi = 0; sqi < 4; ++sqi) {
    if (sqi) __syncthreads();
    if (sq == sqi) {
#pragma unroll
      for (int dt = 0; dt < 4; ++dt)
#pragma unroll
        for (int r = 0; r < 16; ++r) {
          int rp = (r & 3) + 8 * (r >> 2) + 4 * q;
          if (sqi == 0)
            red[head][rp][dt * 32 + tl] = acc[dt][r];
          else
            red[head][rp][dt * 32 + tl] += acc[dt][r];
        }
    }
  }
  __syncthreads();
  // final: u = x_target + bias + sum_h scb*red; LN1; store bf16 x1
  {
    int r = tid >> 5, dg = tid & 31, d0 = dg * 4;
    size_t grow = (size_t)(b * 1024 + tbase + r);
    float4 xa = *(const float4*)(x_target + grow * 128 + d0);
    float4 ga = *(const float4*)(gat_bias + d0);
    float s0 = scb[0][r], s1 = scb[1][r], s2 = scb[2][r], s3 = scb[3][r];
    float4 r0 = *(const float4*)&red[0][r][d0];
    float4 r1 = *(const float4*)&red[1][r][d0];
    float4 r2 = *(const float4*)&red[2][r][d0];
    float4 r3 = *(const float4*)&red[3][r][d0];
    float u[4];
    u[0] = xa.x + ga.x + s0 * r0.x + s1 * r1.x + s2 * r2.x + s3 * r3.x;
    u[1] = xa.y + ga.y + s0 * r0.y + s1 * r1.y + s2 * r2.y + s3 * r3.y;
    u[2] = xa.z + ga.z + s0 * r0.z + s1 * r1.z + s2 * r2.z + s3 * r3.z;
    u[3] = xa.w + ga.w + s0 * r0.w + s1 * r1.w + s2 * r2.w + s3 * r3.w;
    float s = u[0] + u[1] + u[2] + u[3];
    float ss = u[0] * u[0] + u[1] * u[1] + u[2] * u[2] + u[3] * u[3];
#pragma unroll
    for (int off = 1; off < 32; off <<= 1) {
      s += __shfl_xor(s, off);
      ss += __shfl_xor(ss, off);
    }
    float mu = s * (1.f / 128.f);
    float var = ss * (1.f / 128.f) - mu * mu;
    float rstd = rsqrtf(var + 1e-5f);
    float4 g4 = *(const float4*)(ln1_g + d0);
    float4 b4 = *(const float4*)(ln1_b + d0);
    unsigned short o0 = f2bf((u[0] - mu) * rstd * g4.x + b4.x);
    unsigned short o1 = f2bf((u[1] - mu) * rstd * g4.y + b4.y);
    unsigned short o2 = f2bf((u[2] - mu) * rstd * g4.z + b4.z);
    unsigned short o3 = f2bf((u[3] - mu) * rstd * g4.w + b4.w);
    uint2 ov;
    ov.x = (unsigned)o0 | ((unsigned)o1 << 16);
    ov.y = (unsigned)o2 | ((unsigned)o3 << 16);
    *(uint2*)(x1 + grow * 128 + d0) = ov;
  }
}

// ---- K_ffn: x1 -> SwiGLU FFN + residual + LN2 (16 rows/block) ----
__global__ __launch_bounds__(256) void k_ffn(
    const unsigned short* __restrict__ x1,
    const unsigned short* __restrict__ wpP,
    const float* __restrict__ ln2_g, const float* __restrict__ ln2_b,
    float* __restrict__ out) {
  __shared__ unsigned short x1s[16][136];
  __shared__ unsigned short hids[16][136];
  __shared__ float yred[16][128];
  int tid = threadIdx.x;
  int row = tid >> 4, cg = tid & 15;
  size_t rbase = (size_t)blockIdx.x * 16;
  *(s16x8*)&x1s[row][cg * 8] =
      *(const s16x8*)(x1 + (rbase + row) * 128 + cg * 8);
  __syncthreads();
  int w = tid >> 6, lane = tid & 63, n16 = lane & 15, q2 = lane >> 4;
  int nb = w * 32;
  f32x4 accv0 = zero4(), accv1 = zero4(), accg0 = zero4(), accg1 = zero4();
#pragma unroll
  for (int kk = 0; kk < 4; ++kk) {
    s16x8 a = *(const s16x8*)&x1s[n16][kk * 32 + q2 * 8];
    int kg = kk * 4 + q2;
    const unsigned short* bp = wpP + (size_t)(kg * 128 + nb + n16) * 8;
    accv0 = mfma16(a, *(const s16x8*)bp, accv0);
    accv1 = mfma16(a, *(const s16x8*)(bp + 128), accv1);
    accg0 = mfma16(a, *(const s16x8*)(bp + 16384), accg0);
    accg1 = mfma16(a, *(const s16x8*)(bp + 16384 + 128), accg1);
  }
#pragma unroll
  for (int r = 0; r < 4; ++r) {
    int m = q2 * 4 + r;
    float g0 = accg0[r], g1 = accg1[r];
    float h0 = accv0[r] * g0 / (1.f + __expf(-g0));
    float h1 = accv1[r] * g1 / (1.f + __expf(-g1));
    hids[m][nb + n16] = f2bf(h0);
    hids[m][nb + 16 + n16] = f2bf(h1);
  }
  __syncthreads();
  f32x4 acco0 = zero4(), acco1 = zero4();
#pragma unroll
  for (int kk = 0; kk < 4; ++kk) {
    s16x8 a = *(const s16x8*)&hids[n16][kk * 32 + q2 * 8];
    int kg = kk * 4 + q2;
    const unsigned short* bp = wpP + 32768 + (size_t)(kg * 128 + nb + n16) * 8;
    acco0 = mfma16(a, *(const s16x8*)bp, acco0);
    acco1 = mfma16(a, *(const s16x8*)(bp + 128), acco1);
  }
#pragma unroll
  for (int r = 0; r < 4; ++r) {
    int m = q2 * 4 + r;
    yred[m][nb + n16] = bf2f(x1s[m][nb + n16]) + acco0[r];
    yred[m][nb + 16 + n16] = bf2f(x1s[m][nb + 16 + n16]) + acco1[r];
  }
  __syncthreads();
  {
    int k0 = (tid & 15) * 8;
    float y[8];
#pragma unroll
    for (int i = 0; i < 8; ++i) y[i] = yred[row][k0 + i];
    float s = 0.f, ss = 0.f;
#pragma unroll
    for (int i = 0; i < 8; ++i) { s += y[i]; ss += y[i] * y[i]; }
#pragma unroll
    for (int off = 1; off < 16; off <<= 1) { s += __shfl_xor(s, off); ss += __shfl_xor(ss, off); }
    float mu = s * (1.f / 128.f);
    float var = ss * (1.f / 128.f) - mu * mu;
    float rstd = rsqrtf(var + 1e-5f);
    float4 o0, o1;
    o0.x = (y[0] - mu) * rstd * ln2_g[k0] + ln2_b[k0];
    o0.y = (y[1] - mu) * rstd * ln2_g[k0 + 1] + ln2_b[k0 + 1];
    o0.z = (y[2] - mu) * rstd * ln2_g[k0 + 2] + ln2_b[k0 + 2];
    o0.w = (y[3] - mu) * rstd * ln2_g[k0 + 3] + ln2_b[k0 + 3];
    o1.x = (y[4] - mu) * rstd * ln2_g[k0 + 4] + ln2_b[k0 + 4];
    o1.y = (y[5] - mu) * rstd * ln2_g[k0 + 5] + ln2_b[k0 + 5];
    o1.z = (y[6] - mu) * rstd * ln2_g[k0 + 6] + ln2_b[k0 + 6];
    o1.w = (y[7] - mu) * rstd * ln2_g[k0 + 7] + ln2_b[k0 + 7];
    *(float4*)(out + (rbase + row) * 128 + k0) = o0;
    *(float4*)(out + (rbase + row) * 128 + k0 + 4) = o1;
  }
}

// ---------------- launch ----------------
extern "C" void kernel_launch(void* const* d_in, const int* in_sizes, int n_in,
                              void* d_out, int out_size, void* d_ws, size_t ws_size,
                              hipStream_t stream) {
  const float* x_target = (const float*)d_in[0];
  const float* adj      = (const float*)d_in[1];
  const float* x_source = (const float*)d_in[2];
  const float* W_src    = (const float*)d_in[3];
  const float* W_tgt    = (const float*)d_in[4];
  const float* att_src  = (const float*)d_in[5];
  const float* att_tgt  = (const float*)d_in[6];
  const float* gat_bias = (const float*)d_in[7];
  const float* ln1_g    = (const float*)d_in[8];
  const float* ln1_b    = (const float*)d_in[9];
  const float* W_gv     = (const float*)d_in[10];
  const float* W_out    = (const float*)d_in[11];
  const float* ln2_g    = (const float*)d_in[12];
  const float* ln2_b    = (const float*)d_in[13];

  float* ws_f = (float*)d_ws;
  // workspace layout (float-element offsets)
  const size_t OFF_C  = 0;        // csum_tgt [4][128] = 512 f
  const size_t OFF_ES = 512;      // esrc float2 [8][4][1024] = 65536 f
  const size_t OFF_AB = 66048;    // abits32 [8192][32] = 262144 f
  const size_t OFF_X1 = 328192;   // x1 bf16 [8192][128] = 524288 f
  const size_t OFF_HS = 852480;   // h_srcP bf16 [32][131072] = 2097152 f
  unsigned short* x1     = (unsigned short*)(ws_f + OFF_X1);
  unsigned short* h_srcP = (unsigned short*)(ws_f + OFF_HS);
  unsigned short* wpP    = h_srcP + (size_t)4194304;  // 49152 bf16
  unsigned short* W_srcP = wpP + 49152;               // 65536 bf16

  k_pre<<<1476, 256, 0, stream>>>(W_tgt, W_src, att_tgt, W_gv, W_out, adj,
                                  wpP, W_srcP, ws_f + OFF_C,
                                  (unsigned int*)(ws_f + OFF_AB));
  k_hsrc<<<256, 256, 0, stream>>>(x_source, W_srcP, att_src, h_srcP,
                                  ws_f + OFF_ES);
  k_attn<<<256, 1024, 65536, stream>>>(h_srcP, ws_f + OFF_C, ws_f + OFF_ES,
                                       (const unsigned int*)(ws_f + OFF_AB),
                                       x_target, gat_bias, ln1_g, ln1_b, x1);
  k_ffn<<<512, 256, 0, stream>>>(x1, wpP, ln2_g, ln2_b, (float*)d_out);
}

// Round 11
// 154.411 us; speedup vs baseline: 1.1834x; 1.0011x over previous
//
#include <hip/hip_runtime.h>
#include <stdint.h>

// Shapes: B=8, Nt=Ns=1024, D=128, H=4. All I/O float32.

typedef float f32x16 __attribute__((ext_vector_type(16)));
typedef float f32x4 __attribute__((ext_vector_type(4)));
typedef short s16x8 __attribute__((ext_vector_type(8)));
typedef __bf16 bf16x8 __attribute__((ext_vector_type(8)));

__device__ __forceinline__ f32x16 mfma_bf16(s16x8 a, s16x8 b, f32x16 c) {
  return __builtin_amdgcn_mfma_f32_32x32x16_bf16(
      __builtin_bit_cast(bf16x8, a), __builtin_bit_cast(bf16x8, b), c, 0, 0, 0);
}
__device__ __forceinline__ f32x4 mfma16(s16x8 a, s16x8 b, f32x4 c) {
  return __builtin_amdgcn_mfma_f32_16x16x32_bf16(
      __builtin_bit_cast(bf16x8, a), __builtin_bit_cast(bf16x8, b), c, 0, 0, 0);
}

__device__ __forceinline__ unsigned short f2bf(float f) {
  union { float f; unsigned int i; } v; v.f = f;
  return (unsigned short)((v.i + 0x8000u) >> 16);
}
__device__ __forceinline__ float bf2f(unsigned short u) {
  union { unsigned int i; float f; } v; v.i = ((unsigned int)u) << 16; return v.f;
}
__device__ __forceinline__ s16x8 pack8(float4 a, float4 b) {
  s16x8 r;
  r[0] = (short)f2bf(a.x); r[1] = (short)f2bf(a.y);
  r[2] = (short)f2bf(a.z); r[3] = (short)f2bf(a.w);
  r[4] = (short)f2bf(b.x); r[5] = (short)f2bf(b.y);
  r[6] = (short)f2bf(b.z); r[7] = (short)f2bf(b.w);
  return r;
}
__device__ __forceinline__ f32x16 zero16() {
  f32x16 z;
#pragma unroll
  for (int i = 0; i < 16; ++i) z[i] = 0.f;
  return z;
}
__device__ __forceinline__ f32x4 zero4() {
  f32x4 z; z[0] = z[1] = z[2] = z[3] = 0.f; return z;
}

// ---- K_pre: wpP pack | W_src pack | csum_tgt | adj bitmask (ballot-free) ----
__global__ __launch_bounds__(256) void k_pre(
    const float* __restrict__ W_tgt, const float* __restrict__ W_src,
    const float* __restrict__ att_tgt,
    const float* __restrict__ W_gv, const float* __restrict__ W_out,
    const float* __restrict__ adj,
    unsigned short* __restrict__ wpP, unsigned short* __restrict__ W_srcP,
    float* __restrict__ ws_c, unsigned int* __restrict__ abits32) {
  int blk = blockIdx.x, tid = threadIdx.x;
  if (blk < 192) {
    // FFN weights -> tiled bf16: wpP[mat][kg][n][8], mat: 0=val,1=gate,2=out
    int i = blk * 256 + tid;  // 0..49151
    int r = i >> 7, c = i & 127;
    float v = (r < 256) ? W_gv[i] : W_out[i - 32768];
    int mat = (r < 128) ? 0 : ((r < 256) ? 1 : 2);
    int n = r & 127, kg = c >> 3, j = c & 7;
    wpP[mat * 16384 + (kg * 128 + n) * 8 + j] = f2bf(v);
  } else if (blk < 448) {
    // W_src -> tiled bf16 W_srcP[kg][n][8]
    int i = (blk - 192) * 256 + tid;  // 0..65535
    int n = i >> 7, c = i & 127;
    int kg = c >> 3, j = c & 7;
    W_srcP[(kg * 512 + n) * 8 + j] = f2bf(W_src[i]);
  } else if (blk < 452) {
    // csum_tgt[h][k] = sum_d att_tgt[h][d] * W_tgt[h*128+d][k]
    __shared__ float part[2][128];
    int h = blk - 448;
    int k = tid & 127, dh = tid >> 7;
    float acc = 0.f;
#pragma unroll 4
    for (int i = 0; i < 64; ++i) {
      int d = dh * 64 + i;
      acc += att_tgt[h * 128 + d] * W_tgt[(h * 128 + d) * 128 + k];
    }
    part[dh][k] = acc;
    __syncthreads();
    if (tid < 128) ws_c[h * 128 + k] = part[0][k] + part[1][k];
  } else {
    // adj -> bitmask: one thread = one 32-bit word = one 128B line. No cross-lane.
    int g = (blk - 452) * 256 + tid;  // 0..262143
    const float* ap = adj + (size_t)g * 32;
    unsigned int bits = 0;
#pragma unroll
    for (int it = 0; it < 8; ++it) {
      float4 v = *(const float4*)(ap + it * 4);
      bits |= (v.x != 0.f ? 1u : 0u) << (it * 4);
      bits |= (v.y != 0.f ? 1u : 0u) << (it * 4 + 1);
      bits |= (v.z != 0.f ? 1u : 0u) << (it * 4 + 2);
      bits |= (v.w != 0.f ? 1u : 0u) << (it * 4 + 3);
    }
    abits32[g] = bits;
  }
}

// ---- K_hsrc: h_srcP[b*4+h][s/8][d][8] bf16 + a_src -> ES/ES2 epilogue ----
__global__ __launch_bounds__(256) void k_hsrc(
    const float* __restrict__ x_source,
    const unsigned short* __restrict__ W_srcP,
    const float* __restrict__ att_src,
    unsigned short* __restrict__ h_srcP, float* __restrict__ esrc) {
  __shared__ unsigned short As[128][136];
  __shared__ float apart[128];
  int mt = blockIdx.x >> 2, nt = blockIdx.x & 3;  // nt = head
  int nbase = nt * 128;
  int b = mt >> 3, sbase = (mt & 7) * 128;
  int tid = threadIdx.x;
  int w = tid >> 6, lane = tid & 63;
#pragma unroll
  for (int c = tid; c < 2048; c += 256) {
    int r = c >> 4, c8 = (c & 15) * 8;
    const float* src = x_source + ((size_t)(mt * 128 + r)) * 128 + c8;
    *(s16x8*)&As[r][c8] = pack8(*(const float4*)src, *(const float4*)(src + 4));
  }
  __syncthreads();
  int tl = lane & 31, q = lane >> 5;
  int wm = w >> 1, wn = w & 1;
  f32x16 acc00 = zero16(), acc01 = zero16(), acc10 = zero16(), acc11 = zero16();
#pragma unroll
  for (int kk = 0; kk < 8; ++kk) {
    int k = kk * 16 + q * 8;
    int kg = kk * 2 + q;
    s16x8 a0 = *(const s16x8*)&As[wm * 64 + tl][k];
    s16x8 a1 = *(const s16x8*)&As[wm * 64 + 32 + tl][k];
    s16x8 b0 = *(const s16x8*)(W_srcP + (size_t)(kg * 512 + nbase + wn * 64 + tl) * 8);
    s16x8 b1 = *(const s16x8*)(W_srcP + (size_t)(kg * 512 + nbase + wn * 64 + 32 + tl) * 8);
    acc00 = mfma_bf16(a0, b0, acc00);
    acc01 = mfma_bf16(a0, b1, acc01);
    acc10 = mfma_bf16(a1, b0, acc10);
    acc11 = mfma_bf16(a1, b1, acc11);
  }
  // a_src epilogue: a[s] = sum_d h[s][d]*att[head][d]
  {
    float attd0 = att_src[nt * 128 + wn * 64 + tl];
    float attd1 = att_src[nt * 128 + wn * 64 + 32 + tl];
#pragma unroll
    for (int phase = 0; phase < 2; ++phase) {
      __syncthreads();
      if (wn == phase) {
#pragma unroll
        for (int r = 0; r < 16; ++r) {
          int rp = (r & 3) + 8 * (r >> 2) + 4 * q;
          float v0 = acc00[r] * attd0 + acc01[r] * attd1;
          float v1 = acc10[r] * attd0 + acc11[r] * attd1;
#pragma unroll
          for (int off = 1; off < 32; off <<= 1) {
            v0 += __shfl_xor(v0, off);
            v1 += __shfl_xor(v1, off);
          }
          if (tl == 0) {
            if (phase == 0) {
              apart[wm * 64 + rp] = v0;
              apart[wm * 64 + 32 + rp] = v1;
            } else {
              apart[wm * 64 + rp] += v0;
              apart[wm * 64 + 32 + rp] += v1;
            }
          }
        }
      }
    }
    __syncthreads();
    if (tid < 128) {
      float a = apart[tid];
      float2 e = make_float2(__expf(a), __expf(0.2f * a));
      *(float2*)&esrc[((((size_t)(b * 4 + nt)) << 10) | (sbase + tid)) * 2] = e;
    }
  }
  __syncthreads();
#pragma unroll
  for (int r = 0; r < 16; ++r) {
    int rp = (r & 3) + 8 * (r >> 2) + 4 * q;
    As[wn * 64 + tl][wm * 64 + rp] = f2bf(acc00[r]);
    As[wn * 64 + 32 + tl][wm * 64 + rp] = f2bf(acc01[r]);
    As[wn * 64 + tl][wm * 64 + 32 + rp] = f2bf(acc10[r]);
    As[wn * 64 + 32 + tl][wm * 64 + 32 + rp] = f2bf(acc11[r]);
  }
  __syncthreads();
  size_t base = ((size_t)(b * 4 + nt)) << 17;
#pragma unroll
  for (int c = tid; c < 2048; c += 256) {
    int d = c & 127, sgl = c >> 7;
    *(uint4*)(h_srcP + base + (size_t)((sbase >> 3) + sgl) * 1024 + d * 8) =
        *(const uint4*)&As[d][sgl * 8];
  }
}

// ---- K_attn: all 4 heads per block + head-mean + bias + residual + LN1 -> x1 bf16 ----
// grid 256 = b(&7) x tt(>>3); 1024 threads = 16 waves: head = w&3, sq = w>>2.
__global__ __launch_bounds__(1024) void k_attn(
    const unsigned short* __restrict__ h_srcP,
    const float* __restrict__ ws_c, const float* __restrict__ esrc,
    const unsigned int* __restrict__ abits32,
    const float* __restrict__ x_target, const float* __restrict__ gat_bias,
    const float* __restrict__ ln1_g, const float* __restrict__ ln1_b,
    unsigned short* __restrict__ x1) {
  extern __shared__ float dsm[];  // 64 KB: [0,8192f)=es[4][1024][2]; later red[4][32][128]
  __shared__ unsigned int bmask[32][33];
  __shared__ float eab[4][32], ea2b[4][32], scb[4][32];
  __shared__ float zpart[4][4][32];
  int b = blockIdx.x & 7, tt = blockIdx.x >> 3;
  int tbase = tt * 32;
  int tid = threadIdx.x, w = tid >> 6, lane = tid & 63;
  {
    const float* ep = esrc + ((size_t)b << 13);
    *(float4*)&dsm[tid * 8] = *(const float4*)(ep + tid * 8);
    *(float4*)&dsm[tid * 8 + 4] = *(const float4*)(ep + tid * 8 + 4);
  }
  {
    int r = tid >> 5, c = tid & 31;
    bmask[r][c] = abits32[((size_t)(b * 1024 + tbase + r)) * 32 + c];
  }
  // inline a_tgt: wave w computes 8 (h,r) dots; h uniform per wave
  {
    int p0 = w * 8;
    int h = p0 >> 5;
    float2 c2 = *(const float2*)(ws_c + h * 128 + lane * 2);
#pragma unroll
    for (int i = 0; i < 8; ++i) {
      int r = (p0 + i) & 31;
      float2 xv = *(const float2*)(x_target +
                                   ((size_t)(b * 1024 + tbase + r)) * 128 + lane * 2);
      float p = xv.x * c2.x + xv.y * c2.y;
#pragma unroll
      for (int off = 32; off; off >>= 1) p += __shfl_xor(p, off);
      if (lane == 0) {
        eab[h][r] = __expf(p);
        ea2b[h][r] = __expf(0.2f * p);
      }
    }
  }
  __syncthreads();
  int head = w & 3, sq = w >> 2, tl = lane & 31, q = lane >> 5;
  float EA = eab[head][tl], EA2 = ea2b[head][tl];
  f32x16 acc[4];
#pragma unroll
  for (int i = 0; i < 4; ++i) acc[i] = zero16();
  float z = 0.f;
  const float* asl = dsm + (head << 11);
  const unsigned short* bbase = h_srcP + (((size_t)(b * 4 + head)) << 17);
#pragma unroll 2
  for (int kk = 0; kk < 16; ++kk) {
    int sA = sq * 256 + kk * 16 + q * 8;
    const unsigned short* hp = bbase + (size_t)((sA >> 3) * 128 + tl) * 8;
    s16x8 b0 = *(const s16x8*)hp;
    s16x8 b1 = *(const s16x8*)(hp + 256);
    s16x8 b2 = *(const s16x8*)(hp + 512);
    s16x8 b3 = *(const s16x8*)(hp + 768);
    unsigned int wbits = bmask[tl][sA >> 5] >> (sA & 31);
    const float4* ev = (const float4*)&asl[sA * 2];
    float4 e0 = ev[0], e1 = ev[1], e2 = ev[2], e3 = ev[3];
    int4 afw;
#define PAIR(EV, J0, OUT)                                              \
  {                                                                    \
    float q1a = EA * EV.x, q0a = EA2 * EV.y;                           \
    float pa = (q1a >= 1.f) ? q1a : q0a;                               \
    unsigned pau = __float_as_uint(pa) & (0u - ((wbits >> (J0)) & 1u)); \
    float q1b = EA * EV.z, q0b = EA2 * EV.w;                           \
    float pb = (q1b >= 1.f) ? q1b : q0b;                               \
    unsigned pbu = __float_as_uint(pb) & (0u - ((wbits >> (J0 + 1)) & 1u)); \
    z += __uint_as_float(pau) + __uint_as_float(pbu);                  \
    OUT = (int)__builtin_amdgcn_perm(pbu + 0x8000u, pau + 0x8000u, 0x07060302u); \
  }
    PAIR(e0, 0, afw.x)
    PAIR(e1, 2, afw.y)
    PAIR(e2, 4, afw.z)
    PAIR(e3, 6, afw.w)
#undef PAIR
    s16x8 af = __builtin_bit_cast(s16x8, afw);
    acc[0] = mfma_bf16(af, b0, acc[0]);
    acc[1] = mfma_bf16(af, b1, acc[1]);
    acc[2] = mfma_bf16(af, b2, acc[2]);
    acc[3] = mfma_bf16(af, b3, acc[3]);
  }
  z += __shfl_xor(z, 32);
  if (q == 0) zpart[head][sq][tl] = z;
  __syncthreads();  // all waves done with es region
  if (tid < 128) {
    int h = tid >> 5, r = tid & 31;
    float Z = zpart[h][0][r] + zpart[h][1][r] + zpart[h][2][r] + zpart[h][3][r];
    scb[h][r] = (Z > 0.f) ? 0.25f / Z : 0.f;
  }
  float (*red)[32][128] = (float(*)[32][128])dsm;
#pragma unroll
  for (int sqi = 0; sqi < 4; ++sqi) {
    if (sqi) __syncthreads();
    if (sq == sqi) {
#pragma unroll
      for (int dt = 0; dt < 4; ++dt)
#pragma unroll
        for (int r = 0; r < 16; ++r) {
          int rp = (r & 3) + 8 * (r >> 2) + 4 * q;
          if (sqi == 0)
            red[head][rp][dt * 32 + tl] = acc[dt][r];
          else
            red[head][rp][dt * 32 + tl] += acc[dt][r];
        }
    }
  }
  __syncthreads();
  // final: u = x_target + bias + sum_h scb*red; LN1; store bf16 x1
  {
    int r = tid >> 5, dg = tid & 31, d0 = dg * 4;
    size_t grow = (size_t)(b * 1024 + tbase + r);
    float4 xa = *(const float4*)(x_target + grow * 128 + d0);
    float4 ga = *(const float4*)(gat_bias + d0);
    float s0 = scb[0][r], s1 = scb[1][r], s2 = scb[2][r], s3 = scb[3][r];
    float4 r0 = *(const float4*)&red[0][r][d0];
    float4 r1 = *(const float4*)&red[1][r][d0];
    float4 r2 = *(const float4*)&red[2][r][d0];
    float4 r3 = *(const float4*)&red[3][r][d0];
    float u[4];
    u[0] = xa.x + ga.x + s0 * r0.x + s1 * r1.x + s2 * r2.x + s3 * r3.x;
    u[1] = xa.y + ga.y + s0 * r0.y + s1 * r1.y + s2 * r2.y + s3 * r3.y;
    u[2] = xa.z + ga.z + s0 * r0.z + s1 * r1.z + s2 * r2.z + s3 * r3.z;
    u[3] = xa.w + ga.w + s0 * r0.w + s1 * r1.w + s2 * r2.w + s3 * r3.w;
    float s = u[0] + u[1] + u[2] + u[3];
    float ss = u[0] * u[0] + u[1] * u[1] + u[2] * u[2] + u[3] * u[3];
#pragma unroll
    for (int off = 1; off < 32; off <<= 1) {
      s += __shfl_xor(s, off);
      ss += __shfl_xor(ss, off);
    }
    float mu = s * (1.f / 128.f);
    float var = ss * (1.f / 128.f) - mu * mu;
    float rstd = rsqrtf(var + 1e-5f);
    float4 g4 = *(const float4*)(ln1_g + d0);
    float4 b4 = *(const float4*)(ln1_b + d0);
    unsigned short o0 = f2bf((u[0] - mu) * rstd * g4.x + b4.x);
    unsigned short o1 = f2bf((u[1] - mu) * rstd * g4.y + b4.y);
    unsigned short o2 = f2bf((u[2] - mu) * rstd * g4.z + b4.z);
    unsigned short o3 = f2bf((u[3] - mu) * rstd * g4.w + b4.w);
    uint2 ov;
    ov.x = (unsigned)o0 | ((unsigned)o1 << 16);
    ov.y = (unsigned)o2 | ((unsigned)o3 << 16);
    *(uint2*)(x1 + grow * 128 + d0) = ov;
  }
}

// ---- K_ffn: x1 -> SwiGLU FFN + residual + LN2 (16 rows/block) ----
__global__ __launch_bounds__(256) void k_ffn(
    const unsigned short* __restrict__ x1,
    const unsigned short* __restrict__ wpP,
    const float* __restrict__ ln2_g, const float* __restrict__ ln2_b,
    float* __restrict__ out) {
  __shared__ unsigned short x1s[16][136];
  __shared__ unsigned short hids[16][136];
  __shared__ float yred[16][128];
  int tid = threadIdx.x;
  int row = tid >> 4, cg = tid & 15;
  size_t rbase = (size_t)blockIdx.x * 16;
  *(s16x8*)&x1s[row][cg * 8] =
      *(const s16x8*)(x1 + (rbase + row) * 128 + cg * 8);
  __syncthreads();
  int w = tid >> 6, lane = tid & 63, n16 = lane & 15, q2 = lane >> 4;
  int nb = w * 32;
  f32x4 accv0 = zero4(), accv1 = zero4(), accg0 = zero4(), accg1 = zero4();
#pragma unroll
  for (int kk = 0; kk < 4; ++kk) {
    s16x8 a = *(const s16x8*)&x1s[n16][kk * 32 + q2 * 8];
    int kg = kk * 4 + q2;
    const unsigned short* bp = wpP + (size_t)(kg * 128 + nb + n16) * 8;
    accv0 = mfma16(a, *(const s16x8*)bp, accv0);
    accv1 = mfma16(a, *(const s16x8*)(bp + 128), accv1);
    accg0 = mfma16(a, *(const s16x8*)(bp + 16384), accg0);
    accg1 = mfma16(a, *(const s16x8*)(bp + 16384 + 128), accg1);
  }
#pragma unroll
  for (int r = 0; r < 4; ++r) {
    int m = q2 * 4 + r;
    float g0 = accg0[r], g1 = accg1[r];
    float h0 = accv0[r] * g0 / (1.f + __expf(-g0));
    float h1 = accv1[r] * g1 / (1.f + __expf(-g1));
    hids[m][nb + n16] = f2bf(h0);
    hids[m][nb + 16 + n16] = f2bf(h1);
  }
  __syncthreads();
  f32x4 acco0 = zero4(), acco1 = zero4();
#pragma unroll
  for (int kk = 0; kk < 4; ++kk) {
    s16x8 a = *(const s16x8*)&hids[n16][kk * 32 + q2 * 8];
    int kg = kk * 4 + q2;
    const unsigned short* bp = wpP + 32768 + (size_t)(kg * 128 + nb + n16) * 8;
    acco0 = mfma16(a, *(const s16x8*)bp, acco0);
    acco1 = mfma16(a, *(const s16x8*)(bp + 128), acco1);
  }
#pragma unroll
  for (int r = 0; r < 4; ++r) {
    int m = q2 * 4 + r;
    yred[m][nb + n16] = bf2f(x1s[m][nb + n16]) + acco0[r];
    yred[m][nb + 16 + n16] = bf2f(x1s[m][nb + 16 + n16]) + acco1[r];
  }
  __syncthreads();
  {
    int k0 = (tid & 15) * 8;
    float y[8];
#pragma unroll
    for (int i = 0; i < 8; ++i) y[i] = yred[row][k0 + i];
    float s = 0.f, ss = 0.f;
#pragma unroll
    for (int i = 0; i < 8; ++i) { s += y[i]; ss += y[i] * y[i]; }
#pragma unroll
    for (int off = 1; off < 16; off <<= 1) { s += __shfl_xor(s, off); ss += __shfl_xor(ss, off); }
    float mu = s * (1.f / 128.f);
    float var = ss * (1.f / 128.f) - mu * mu;
    float rstd = rsqrtf(var + 1e-5f);
    float4 o0, o1;
    o0.x = (y[0] - mu) * rstd * ln2_g[k0] + ln2_b[k0];
    o0.y = (y[1] - mu) * rstd * ln2_g[k0 + 1] + ln2_b[k0 + 1];
    o0.z = (y[2] - mu) * rstd * ln2_g[k0 + 2] + ln2_b[k0 + 2];
    o0.w = (y[3] - mu) * rstd * ln2_g[k0 + 3] + ln2_b[k0 + 3];
    o1.x = (y[4] - mu) * rstd * ln2_g[k0 + 4] + ln2_b[k0 + 4];
    o1.y = (y[5] - mu) * rstd * ln2_g[k0 + 5] + ln2_b[k0 + 5];
    o1.z = (y[6] - mu) * rstd * ln2_g[k0 + 6] + ln2_b[k0 + 6];
    o1.w = (y[7] - mu) * rstd * ln2_g[k0 + 7] + ln2_b[k0 + 7];
    *(float4*)(out + (rbase + row) * 128 + k0) = o0;
    *(float4*)(out + (rbase + row) * 128 + k0 + 4) = o1;
  }
}

// ---------------- launch ----------------
extern "C" void kernel_launch(void* const* d_in, const int* in_sizes, int n_in,
                              void* d_out, int out_size, void* d_ws, size_t ws_size,
                              hipStream_t stream) {
  const float* x_target = (const float*)d_in[0];
  const float* adj      = (const float*)d_in[1];
  const float* x_source = (const float*)d_in[2];
  const float* W_src    = (const float*)d_in[3];
  const float* W_tgt    = (const float*)d_in[4];
  const float* att_src  = (const float*)d_in[5];
  const float* att_tgt  = (const float*)d_in[6];
  const float* gat_bias = (const float*)d_in[7];
  const float* ln1_g    = (const float*)d_in[8];
  const float* ln1_b    = (const float*)d_in[9];
  const float* W_gv     = (const float*)d_in[10];
  const float* W_out    = (const float*)d_in[11];
  const float* ln2_g    = (const float*)d_in[12];
  const float* ln2_b    = (const float*)d_in[13];

  float* ws_f = (float*)d_ws;
  // workspace layout (float-element offsets)
  const size_t OFF_C  = 0;        // csum_tgt [4][128] = 512 f
  const size_t OFF_ES = 512;      // esrc float2 [8][4][1024] = 65536 f
  const size_t OFF_AB = 66048;    // abits32 [8192][32] = 262144 f
  const size_t OFF_X1 = 328192;   // x1 bf16 [8192][128] = 524288 f
  const size_t OFF_HS = 852480;   // h_srcP bf16 [32][131072] = 2097152 f
  unsigned short* x1     = (unsigned short*)(ws_f + OFF_X1);
  unsigned short* h_srcP = (unsigned short*)(ws_f + OFF_HS);
  unsigned short* wpP    = h_srcP + (size_t)4194304;  // 49152 bf16
  unsigned short* W_srcP = wpP + 49152;               // 65536 bf16

  k_pre<<<1476, 256, 0, stream>>>(W_tgt, W_src, att_tgt, W_gv, W_out, adj,
                                  wpP, W_srcP, ws_f + OFF_C,
                                  (unsigned int*)(ws_f + OFF_AB));
  k_hsrc<<<256, 256, 0, stream>>>(x_source, W_srcP, att_src, h_srcP,
                                  ws_f + OFF_ES);
  k_attn<<<256, 1024, 65536, stream>>>(h_srcP, ws_f + OFF_C, ws_f + OFF_ES,
                                       (const unsigned int*)(ws_f + OFF_AB),
                                       x_target, gat_bias, ln1_g, ln1_b, x1);
  k_ffn<<<512, 256, 0, stream>>>(x1, wpP, ln2_g, ln2_b, (float*)d_out);
}